// Round 1
// baseline (44.581 us; speedup 1.0000x reference)
//
#include <hip/hip_runtime.h>

#define EPS 1e-10f

// out[n] = exp( sum_f lw[f] * log(|iw[f]*x[n,f]| + EPS) ), N rows, F=64.
// Thread t handles float4 quad (t&15) of row (t>>4). 16 lanes per row,
// 4 rows per wave iteration. Coalesced 16B/lane loads.
__global__ __launch_bounds__(256) void pta_log_kernel(
    const float* __restrict__ x,
    const float* __restrict__ iw,
    const float* __restrict__ lw,
    float* __restrict__ out,
    int n_quads)  // = N * 16
{
    const int tid = blockIdx.x * blockDim.x + threadIdx.x;
    const int nthreads = gridDim.x * blockDim.x;   // multiple of 16
    const int quad = tid & 15;

    // loop-invariant per-thread weights (quad is fixed across the stride loop)
    const float4 w4 = reinterpret_cast<const float4*>(iw)[quad];
    const float4 l4 = reinterpret_cast<const float4*>(lw)[quad];

    for (int t = tid; t < n_quads; t += nthreads) {
        const float4 xv = reinterpret_cast<const float4*>(x)[t];

        float s;
        s  = l4.x * __logf(fabsf(w4.x * xv.x) + EPS);
        s  = fmaf(l4.y, __logf(fabsf(w4.y * xv.y) + EPS), s);
        s  = fmaf(l4.z, __logf(fabsf(w4.z * xv.z) + EPS), s);
        s  = fmaf(l4.w, __logf(fabsf(w4.w * xv.w) + EPS), s);

        // reduce across the 16 lanes of this row (groups aligned in wave64)
        s += __shfl_xor(s, 1);
        s += __shfl_xor(s, 2);
        s += __shfl_xor(s, 4);
        s += __shfl_xor(s, 8);

        if (quad == 0) out[t >> 4] = __expf(s);
    }
}

extern "C" void kernel_launch(void* const* d_in, const int* in_sizes, int n_in,
                              void* d_out, int out_size, void* d_ws, size_t ws_size,
                              hipStream_t stream) {
    const float* x  = (const float*)d_in[0];   // [N, 64] f32
    const float* iw = (const float*)d_in[1];   // [64] f32
    const float* lw = (const float*)d_in[2];   // [1, 64] f32 (flat 64)
    float* out = (float*)d_out;                // [N] f32

    const int N = in_sizes[0] / 64;
    const int n_quads = N * 16;

    const int block = 256;
    const int grid = 2048;  // ~8 blocks/CU worth; grid-stride covers the rest

    pta_log_kernel<<<grid, block, 0, stream>>>(x, iw, lw, out, n_quads);
}